// Round 13
// baseline (1274.202 us; speedup 1.0000x reference)
//
#include <hip/hip_runtime.h>
#include <math.h>

// KNNGraph(2) on N=16384 points, D=64, fp32.
// adjacency = I + one-hot(nearest other neighbor) per row.
// argmin_j (sq[j] - 2*dot(x_i,x_j)), j != i.
//
// R7: split-bf16 MFMA (dot = hi*hi + lo*hi + hi*lo), lane-owns-one-i argmin.
// R8: contiguous zero rows. R9: pre-split Xs -> pure-copy stage (knn ~300us).
// R10: LDS-free path regressed (vmcnt in-order coupling). Reverted.
// R11/R12: reg-prefetch double-buffer + NONTEMPORAL zero stores -> +124us
//      regression vs R9.
// R13: un-bundle. Keep the reg-prefetch (loads issued before stores ->
//      counted vmcnt wait at stage, no store drain); REVERT nontemporal to
//      plain stores (fill kernel proves write-back L2 coalescing reaches
//      6.2 TB/s; nt's no-allocate forces sub-line write-through = the
//      regression suspect).
//      (~690us harness re-poison fill + ~85us fixed overhead are immovable.)

#define NPTS 16384
#define DIM 64
#define BI 64           // i-rows per block (4 waves x 16)
#define BJ 128          // j-cols per tile
#define NTHR 256        // 4 waves
#define JSPLIT 4        // j-stripes; grid = 256*4 = 1024 = 4 blocks/CU exact
#define JRANGE (NPTS / JSPLIT)   // 4096
#define NJT (JRANGE / BJ)        // 32 tiles
#define RPITCH 128      // shorts per Xs/LDS row: 64 hi + 64 lo (256 B)

typedef __attribute__((ext_vector_type(8))) short s16x8;   // 8 bf16 (4 VGPRs)
typedef __attribute__((ext_vector_type(4))) float f32x4;   // MFMA C/D

// LDS-only barrier: orders ds ops but NOT outstanding global stores/loads.
#define LDS_BARRIER() asm volatile("s_waitcnt lgkmcnt(0)\n\ts_barrier" ::: "memory")

__device__ __forceinline__ ushort bf16_rn(float x) {
  unsigned u = __float_as_uint(x);
  u += 0x7fffu + ((u >> 16) & 1u);   // round-to-nearest-even
  return (ushort)(u >> 16);
}
__device__ __forceinline__ float bf16_f(ushort h) {
  return __uint_as_float((unsigned)h << 16);
}

// X fp32 [N][64] -> Xs shorts [N][128]: row = 64 hi-bf16 | 64 lo-bf16.
__global__ void split_kernel(const float* __restrict__ X, short* __restrict__ Xs) {
  const int tid = threadIdx.x;
  const int r0 = blockIdx.x * 64;
#pragma unroll
  for (int p = 0; p < 4; ++p) {
    int f4 = tid + NTHR * p;            // 0..1023
    int r = f4 >> 4, c = f4 & 15;       // row in [0,64), float4 col
    float4 v = ((const float4*)(X + (size_t)(r0 + r) * DIM))[c];
    ushort hx = bf16_rn(v.x), hy = bf16_rn(v.y), hz = bf16_rn(v.z), hw = bf16_rn(v.w);
    ushort lx = bf16_rn(v.x - bf16_f(hx)), ly = bf16_rn(v.y - bf16_f(hy)),
           lz = bf16_rn(v.z - bf16_f(hz)), lw = bf16_rn(v.w - bf16_f(hw));
    short* dst = Xs + (size_t)(r0 + r) * RPITCH;
    *(uint2*)(dst + 4 * c) = make_uint2((unsigned)hx | ((unsigned)hy << 16),
                                        (unsigned)hz | ((unsigned)hw << 16));
    *(uint2*)(dst + 64 + 4 * c) = make_uint2((unsigned)lx | ((unsigned)ly << 16),
                                             (unsigned)lz | ((unsigned)lw << 16));
  }
}

__global__ void sq_kernel(const float* __restrict__ X, float* __restrict__ sqout) {
  int i = blockIdx.x * NTHR + threadIdx.x;
  const float4* x4 = (const float4*)(X + (size_t)i * DIM);
  float s = 0.f;
#pragma unroll
  for (int k = 0; k < DIM / 4; ++k) {
    float4 v = x4[k];
    s = fmaf(v.x, v.x, s); s = fmaf(v.y, v.y, s);
    s = fmaf(v.z, v.z, s); s = fmaf(v.w, v.w, s);
  }
  sqout[i] = s;
}

__global__ __launch_bounds__(NTHR, 4) void knn_kernel(
    const short* __restrict__ Xs, const float* __restrict__ sqn,
    float* __restrict__ out, float* __restrict__ cand_val, int* __restrict__ cand_idx) {
  __shared__ __align__(16) short Bs[BJ * RPITCH];   // 32768 B, swizzled
  __shared__ float sqt[BJ];                         // 512 B -> 4 blocks/CU

  const int tid = threadIdx.x;
  const int lane = tid & 63;
  const int wid = tid >> 6;       // wave id 0..3 -> i-subtile
  const int li = lane & 15;       // this lane's i within the wave's 16
  const int g = lane >> 4;        // k-slot group / j-quad group
  const int ib = blockIdx.x >> 2; // / JSPLIT
  const int jh = blockIdx.x & 3;  // % JSPLIT
  const int i0 = ib * BI;
  const int j0base = jh * JRANGE;
  const int i_glob = i0 + wid * 16 + li;
  const size_t z0 = (size_t)jh * JRANGE;   // contiguous zero-stripe col base

  // i-side fragments (MFMA B-operand), resident all kernel. Lane holds
  // d = 8g+e of hi/lo for halves A (d 0..31) and B (d 32..63).
  const short* xi = Xs + (size_t)i_glob * RPITCH;
  s16x8 ihiA, ihiB, iloA, iloB;
  {
    uint4 t;
    t = *(const uint4*)(xi + 8 * g);        ihiA = *(s16x8*)&t;
    t = *(const uint4*)(xi + 32 + 8 * g);   ihiB = *(s16x8*)&t;
    t = *(const uint4*)(xi + 64 + 8 * g);   iloA = *(s16x8*)&t;
    t = *(const uint4*)(xi + 96 + 8 * g);   iloB = *(s16x8*)&t;
  }

  float bv = INFINITY;
  int bix = 0x7fffffff;

  // Prefetch tile 0 into registers (loads are the OLDEST vmem ops).
  uint4 pf[8];
  float sqr;
  {
    const uint4* src = (const uint4*)(Xs + (size_t)j0base * RPITCH);
#pragma unroll
    for (int p = 0; p < 8; ++p) pf[p] = src[tid + NTHR * p];
    sqr = sqn[j0base + (tid & 127)];
  }

#pragma unroll 1
  for (int jt = 0; jt < NJT; ++jt) {
    const int j0 = j0base + jt * BJ;
    LDS_BARRIER();   // WAR: previous tile's ds_reads retired
    // Stage from registers: 16-B chunk (r,c) -> LDS chunk c^(r&7) of row r
    // (XOR swizzle, conflict-free on write and fragment read). The vmcnt
    // wait here targets loads issued a FULL TILE ago (older than every
    // outstanding zero-store) -> counted wait, no store drain.
    {
#pragma unroll
      for (int p = 0; p < 8; ++p) {
        int ck = tid + NTHR * p;          // 0..2047 chunk index
        int r = ck >> 4, c = ck & 15;
        *(uint4*)(&Bs[r * RPITCH + ((c ^ (r & 7)) << 3)]) = pf[p];
      }
      if (tid < BJ) sqt[tid] = sqr;
    }
    LDS_BARRIER();   // Bs/sqt ready

    // Issue NEXT tile's prefetch now -- before any zero-store of this tile,
    // so these loads stay older than all stores issued below.
    {
      const int jtn = (jt + 1 < NJT) ? jt + 1 : 0;   // tail: benign reload
      const uint4* src = (const uint4*)(Xs + (size_t)(j0base + jtn * BJ) * RPITCH);
#pragma unroll
      for (int p = 0; p < 8; ++p) pf[p] = src[tid + NTHR * p];
      sqr = sqn[j0base + jtn * BJ + (tid & 127)];
    }

    // 8 j-subtiles of 16: 4 swizzled ds_read_b128 + 6 MFMAs + argmin each,
    // plus ONE interleaved PLAIN zero-store (16-KB contiguous rows
    // i0+2*jt..+1, cols [jh*4096,+4096)). Write-back L2 coalesces these.
#pragma unroll 2
    for (int s = 0; s < BJ / 16; ++s) {
      {
        int f4 = tid + NTHR * s;          // 0..2047
        int zr = f4 >> 10, zc = f4 & 1023;
        *(float4*)(out + (size_t)(i0 + 2 * jt + zr) * NPTS + z0 + (size_t)zc * 4) =
            make_float4(0.f, 0.f, 0.f, 0.f);
      }
      const short* jrow = &Bs[(16 * s + li) * RPITCH];
      const int sw = (li & 7);            // row-XOR for this lane's j-row
      s16x8 jhiA = *(const s16x8*)(jrow + (((g) ^ sw) << 3));
      s16x8 jhiB = *(const s16x8*)(jrow + (((4 + g) ^ sw) << 3));
      s16x8 jloA = *(const s16x8*)(jrow + (((8 + g) ^ sw) << 3));
      s16x8 jloB = *(const s16x8*)(jrow + (((12 + g) ^ sw) << 3));
      f32x4 sqv = *(const f32x4*)(&sqt[16 * s + 4 * g]);
      f32x4 acc = {0.f, 0.f, 0.f, 0.f};
      acc = __builtin_amdgcn_mfma_f32_16x16x32_bf16(jhiA, ihiA, acc, 0, 0, 0);
      acc = __builtin_amdgcn_mfma_f32_16x16x32_bf16(jhiB, ihiB, acc, 0, 0, 0);
      acc = __builtin_amdgcn_mfma_f32_16x16x32_bf16(jloA, ihiA, acc, 0, 0, 0);
      acc = __builtin_amdgcn_mfma_f32_16x16x32_bf16(jloB, ihiB, acc, 0, 0, 0);
      acc = __builtin_amdgcn_mfma_f32_16x16x32_bf16(jhiA, iloA, acc, 0, 0, 0);
      acc = __builtin_amdgcn_mfma_f32_16x16x32_bf16(jhiB, iloB, acc, 0, 0, 0);
      // Lane owns i = i_glob; rows r of this lane are j = j0+16s+4g+r
      // (j ascends per lane -> strict < keeps smallest j on ties).
#pragma unroll
      for (int r = 0; r < 4; ++r) {
        float d2 = fmaf(-2.f, acc[r], sqv[r]);
        int j = j0 + 16 * s + 4 * g + r;
        if (j != i_glob && d2 < bv) { bv = d2; bix = j; }
      }
    }
  }

  // Reduce the 4 g-partitions (lanes l, l^16, l^32 hold same i).
  {
    float ov = __shfl_xor(bv, 16, 64);
    int oi = __shfl_xor(bix, 16, 64);
    if (ov < bv || (ov == bv && oi < bix)) { bv = ov; bix = oi; }
    ov = __shfl_xor(bv, 32, 64);
    oi = __shfl_xor(bix, 32, 64);
    if (ov < bv || (ov == bv && oi < bix)) { bv = ov; bix = oi; }
  }
  if (g == 0) {   // lanes 0..15: one writer per i
    cand_val[(size_t)i_glob * JSPLIT + jh] = bv;
    cand_idx[(size_t)i_glob * JSPLIT + jh] = bix;
  }
}

__global__ void merge_kernel(const float* __restrict__ cand_val,
                             const int* __restrict__ cand_idx,
                             float* __restrict__ out) {
  int i = blockIdx.x * NTHR + threadIdx.x;
  float bv = INFINITY;
  int bi = 0x7fffffff;
#pragma unroll
  for (int s = 0; s < JSPLIT; ++s) {
    float v = cand_val[(size_t)i * JSPLIT + s];
    int ix = cand_idx[(size_t)i * JSPLIT + s];
    if (v < bv || (v == bv && ix < bi)) { bv = v; bi = ix; }
  }
  out[(size_t)i * NPTS + i] = 1.0f;   // self is always nearest (dist ~ 0)
  out[(size_t)i * NPTS + bi] = 1.0f;  // nearest other neighbor
}

extern "C" void kernel_launch(void* const* d_in, const int* in_sizes, int n_in,
                              void* d_out, int out_size, void* d_ws, size_t ws_size,
                              hipStream_t stream) {
  const float* X = (const float*)d_in[0];
  float* out = (float*)d_out;

  // Workspace: sq[N] 64KB | cand_val 256KB | cand_idx 256KB | Xs 4MB
  float* sq = (float*)d_ws;
  float* cand_val = sq + NPTS;
  int* cand_idx = (int*)(cand_val + (size_t)NPTS * JSPLIT);
  short* Xs = (short*)(cand_idx + (size_t)NPTS * JSPLIT);

  split_kernel<<<NPTS / 64, NTHR, 0, stream>>>(X, Xs);
  sq_kernel<<<NPTS / NTHR, NTHR, 0, stream>>>(X, sq);
  knn_kernel<<<(NPTS / BI) * JSPLIT, NTHR, 0, stream>>>(Xs, sq, out, cand_val, cand_idx);
  merge_kernel<<<NPTS / NTHR, NTHR, 0, stream>>>(cand_val, cand_idx, out);
}

// Round 14
// 1086.791 us; speedup vs baseline: 1.1724x; 1.1724x over previous
//
#include <hip/hip_runtime.h>
#include <math.h>

// KNNGraph(2) on N=16384 points, D=64, fp32.
// adjacency = I + one-hot(nearest other neighbor) per row.
// argmin_j (sq[j] - 2*dot(x_i,x_j)), j != i.
//
// R7: split-bf16 MFMA (dot = hi*hi + lo*hi + hi*lo), lane-owns-one-i argmin.
// R8: contiguous zero rows. R9: pre-split Xs -> pure-copy stage. BEST: 1083us.
// R10: LDS-free path regressed (vmcnt in-order coupling). Reverted.
// R12/R13: reg-prefetch regressed both with NT (1207) and plain (1274) stores
//      -> prefetch itself is net-negative (VGPR pressure + conservative
//      cross-barrier vmcnt scheduling). Three pipelining attempts all lost to
//      the compiler's own schedule (the m99-m141 lesson).
// R14: EXACT R9 knn (proven best) + fuse split+sq into one prep_kernel
//      (single X pass, 16-lane shfl row-sum) to shave a launch + a read.
//      (~690us harness re-poison fill + fixed overhead are immovable.)

#define NPTS 16384
#define DIM 64
#define BI 64           // i-rows per block (4 waves x 16)
#define BJ 128          // j-cols per tile
#define NTHR 256        // 4 waves
#define JSPLIT 4        // j-stripes; grid = 256*4 = 1024 = 4 blocks/CU exact
#define JRANGE (NPTS / JSPLIT)   // 4096
#define NJT (JRANGE / BJ)        // 32 tiles
#define RPITCH 128      // shorts per Xs/LDS row: 64 hi + 64 lo (256 B)

typedef __attribute__((ext_vector_type(8))) short s16x8;   // 8 bf16 (4 VGPRs)
typedef __attribute__((ext_vector_type(4))) float f32x4;   // MFMA C/D

// LDS-only barrier: orders ds ops but NOT outstanding global stores/loads.
#define LDS_BARRIER() asm volatile("s_waitcnt lgkmcnt(0)\n\ts_barrier" ::: "memory")

__device__ __forceinline__ ushort bf16_rn(float x) {
  unsigned u = __float_as_uint(x);
  u += 0x7fffu + ((u >> 16) & 1u);   // round-to-nearest-even
  return (ushort)(u >> 16);
}
__device__ __forceinline__ float bf16_f(ushort h) {
  return __uint_as_float((unsigned)h << 16);
}

// Fused prep: X fp32 [N][64] -> Xs shorts [N][128] (64 hi | 64 lo bf16)
// AND sq[i] = ||x_i||^2, in one pass over X. Row r is handled by 16
// consecutive lanes (within one wave) -> shfl_xor row-sum.
__global__ void prep_kernel(const float* __restrict__ X, short* __restrict__ Xs,
                            float* __restrict__ sqout) {
  const int tid = threadIdx.x;
  const int r0 = blockIdx.x * 64;
#pragma unroll
  for (int p = 0; p < 4; ++p) {
    int f4 = tid + NTHR * p;            // 0..1023
    int r = f4 >> 4, c = f4 & 15;       // row in [0,64), float4 col
    float4 v = ((const float4*)(X + (size_t)(r0 + r) * DIM))[c];
    ushort hx = bf16_rn(v.x), hy = bf16_rn(v.y), hz = bf16_rn(v.z), hw = bf16_rn(v.w);
    ushort lx = bf16_rn(v.x - bf16_f(hx)), ly = bf16_rn(v.y - bf16_f(hy)),
           lz = bf16_rn(v.z - bf16_f(hz)), lw = bf16_rn(v.w - bf16_f(hw));
    short* dst = Xs + (size_t)(r0 + r) * RPITCH;
    *(uint2*)(dst + 4 * c) = make_uint2((unsigned)hx | ((unsigned)hy << 16),
                                        (unsigned)hz | ((unsigned)hw << 16));
    *(uint2*)(dst + 64 + 4 * c) = make_uint2((unsigned)lx | ((unsigned)ly << 16),
                                             (unsigned)lz | ((unsigned)lw << 16));
    // Row-sum of squares across the 16 lanes owning row r (fp32 source).
    float s = v.x * v.x + v.y * v.y + v.z * v.z + v.w * v.w;
    s += __shfl_xor(s, 1, 64);
    s += __shfl_xor(s, 2, 64);
    s += __shfl_xor(s, 4, 64);
    s += __shfl_xor(s, 8, 64);
    if (c == 0) sqout[r0 + r] = s;
  }
}

__global__ __launch_bounds__(NTHR, 4) void knn_kernel(
    const short* __restrict__ Xs, const float* __restrict__ sqn,
    float* __restrict__ out, float* __restrict__ cand_val, int* __restrict__ cand_idx) {
  __shared__ __align__(16) short Bs[BJ * RPITCH];   // 32768 B, swizzled
  __shared__ float sqt[BJ];                         // 512 B -> 4 blocks/CU

  const int tid = threadIdx.x;
  const int lane = tid & 63;
  const int wid = tid >> 6;       // wave id 0..3 -> i-subtile
  const int li = lane & 15;       // this lane's i within the wave's 16
  const int g = lane >> 4;        // k-slot group / j-quad group
  const int ib = blockIdx.x >> 2; // / JSPLIT
  const int jh = blockIdx.x & 3;  // % JSPLIT
  const int i0 = ib * BI;
  const int j0base = jh * JRANGE;
  const int i_glob = i0 + wid * 16 + li;
  const size_t z0 = (size_t)jh * JRANGE;   // contiguous zero-stripe col base

  // i-side fragments (MFMA B-operand), resident all kernel. Lane holds
  // d = 8g+e of hi/lo for halves A (d 0..31) and B (d 32..63).
  const short* xi = Xs + (size_t)i_glob * RPITCH;
  s16x8 ihiA, ihiB, iloA, iloB;
  {
    uint4 t;
    t = *(const uint4*)(xi + 8 * g);        ihiA = *(s16x8*)&t;
    t = *(const uint4*)(xi + 32 + 8 * g);   ihiB = *(s16x8*)&t;
    t = *(const uint4*)(xi + 64 + 8 * g);   iloA = *(s16x8*)&t;
    t = *(const uint4*)(xi + 96 + 8 * g);   iloB = *(s16x8*)&t;
  }

  float bv = INFINITY;
  int bix = 0x7fffffff;

#pragma unroll 1
  for (int jt = 0; jt < NJT; ++jt) {
    const int j0 = j0base + jt * BJ;
    LDS_BARRIER();   // WAR: previous tile's ds_reads retired
    // Stage j-tile: pure 32-KB copy, no arithmetic. 16-B chunk (r,c) of the
    // global row lands at LDS chunk c^(r&7) of LDS row r (XOR swizzle ->
    // conflict-free fragment reads below; writes also uniform over banks).
    {
      const uint4* src = (const uint4*)(Xs + (size_t)j0 * RPITCH);
#pragma unroll
      for (int p = 0; p < 8; ++p) {
        int ck = tid + NTHR * p;          // 0..2047 chunk index
        int r = ck >> 4, c = ck & 15;
        uint4 v = src[ck];
        *(uint4*)(&Bs[r * RPITCH + ((c ^ (r & 7)) << 3)]) = v;
      }
      if (tid < BJ) sqt[tid] = sqn[j0 + tid];
    }
    LDS_BARRIER();   // Bs/sqt ready; zero stream keeps flowing

    // 8 j-subtiles of 16: 4 swizzled ds_read_b128 + 1 sq read + 6 MFMAs each,
    // plus ONE interleaved zero-store (spreads store-queue pressure).
    // D[j,i] += hi_j*hi_i + lo_j*hi_i + hi_j*lo_i.
#pragma unroll 2
    for (int s = 0; s < BJ / 16; ++s) {
      // Interleaved zero: 16-B chunk #(tid + 256*s) of this tile's 2 rows
      // (rows i0+2*jt..+1, cols [jh*4096,+4096) -- 16-KB contiguous/row).
      {
        int f4 = tid + NTHR * s;          // 0..2047
        int zr = f4 >> 10, zc = f4 & 1023;
        *(float4*)(out + (size_t)(i0 + 2 * jt + zr) * NPTS + z0 + (size_t)zc * 4) =
            make_float4(0.f, 0.f, 0.f, 0.f);
      }
      const short* jrow = &Bs[(16 * s + li) * RPITCH];
      const int sw = (li & 7);            // row-XOR for this lane's j-row
      s16x8 jhiA = *(const s16x8*)(jrow + (((g) ^ sw) << 3));
      s16x8 jhiB = *(const s16x8*)(jrow + (((4 + g) ^ sw) << 3));
      s16x8 jloA = *(const s16x8*)(jrow + (((8 + g) ^ sw) << 3));
      s16x8 jloB = *(const s16x8*)(jrow + (((12 + g) ^ sw) << 3));
      f32x4 sqv = *(const f32x4*)(&sqt[16 * s + 4 * g]);
      f32x4 acc = {0.f, 0.f, 0.f, 0.f};
      acc = __builtin_amdgcn_mfma_f32_16x16x32_bf16(jhiA, ihiA, acc, 0, 0, 0);
      acc = __builtin_amdgcn_mfma_f32_16x16x32_bf16(jhiB, ihiB, acc, 0, 0, 0);
      acc = __builtin_amdgcn_mfma_f32_16x16x32_bf16(jloA, ihiA, acc, 0, 0, 0);
      acc = __builtin_amdgcn_mfma_f32_16x16x32_bf16(jloB, ihiB, acc, 0, 0, 0);
      acc = __builtin_amdgcn_mfma_f32_16x16x32_bf16(jhiA, iloA, acc, 0, 0, 0);
      acc = __builtin_amdgcn_mfma_f32_16x16x32_bf16(jhiB, iloB, acc, 0, 0, 0);
      // Lane owns i = i_glob; rows r of this lane are j = j0+16s+4g+r
      // (j ascends per lane -> strict < keeps smallest j on ties).
#pragma unroll
      for (int r = 0; r < 4; ++r) {
        float d2 = fmaf(-2.f, acc[r], sqv[r]);
        int j = j0 + 16 * s + 4 * g + r;
        if (j != i_glob && d2 < bv) { bv = d2; bix = j; }
      }
    }
  }

  // Reduce the 4 g-partitions (lanes l, l^16, l^32 hold same i).
  {
    float ov = __shfl_xor(bv, 16, 64);
    int oi = __shfl_xor(bix, 16, 64);
    if (ov < bv || (ov == bv && oi < bix)) { bv = ov; bix = oi; }
    ov = __shfl_xor(bv, 32, 64);
    oi = __shfl_xor(bix, 32, 64);
    if (ov < bv || (ov == bv && oi < bix)) { bv = ov; bix = oi; }
  }
  if (g == 0) {   // lanes 0..15: one writer per i
    cand_val[(size_t)i_glob * JSPLIT + jh] = bv;
    cand_idx[(size_t)i_glob * JSPLIT + jh] = bix;
  }
}

__global__ void merge_kernel(const float* __restrict__ cand_val,
                             const int* __restrict__ cand_idx,
                             float* __restrict__ out) {
  int i = blockIdx.x * NTHR + threadIdx.x;
  float bv = INFINITY;
  int bi = 0x7fffffff;
#pragma unroll
  for (int s = 0; s < JSPLIT; ++s) {
    float v = cand_val[(size_t)i * JSPLIT + s];
    int ix = cand_idx[(size_t)i * JSPLIT + s];
    if (v < bv || (v == bv && ix < bi)) { bv = v; bi = ix; }
  }
  out[(size_t)i * NPTS + i] = 1.0f;   // self is always nearest (dist ~ 0)
  out[(size_t)i * NPTS + bi] = 1.0f;  // nearest other neighbor
}

extern "C" void kernel_launch(void* const* d_in, const int* in_sizes, int n_in,
                              void* d_out, int out_size, void* d_ws, size_t ws_size,
                              hipStream_t stream) {
  const float* X = (const float*)d_in[0];
  float* out = (float*)d_out;

  // Workspace: sq[N] 64KB | cand_val 256KB | cand_idx 256KB | Xs 4MB
  float* sq = (float*)d_ws;
  float* cand_val = sq + NPTS;
  int* cand_idx = (int*)(cand_val + (size_t)NPTS * JSPLIT);
  short* Xs = (short*)(cand_idx + (size_t)NPTS * JSPLIT);

  prep_kernel<<<NPTS / 64, NTHR, 0, stream>>>(X, Xs, sq);
  knn_kernel<<<(NPTS / BI) * JSPLIT, NTHR, 0, stream>>>(Xs, sq, out, cand_val, cand_idx);
  merge_kernel<<<NPTS / NTHR, NTHR, 0, stream>>>(cand_val, cand_idx, out);
}